// Round 12
// baseline (454.471 us; speedup 1.0000x reference)
//
#include <hip/hip_runtime.h>
#include <hip/hip_bf16.h>
#include <hip/hip_fp8.h>

#define NNODES 40000
#define MPAD   40192   // 157 * 256
#define NEDGES 640000
#define FIN    128
#define HID    512
#define NGRAPH 64

typedef __attribute__((ext_vector_type(8))) short bf16x8;
typedef __attribute__((ext_vector_type(4))) float f32x4;
typedef __attribute__((ext_vector_type(2))) float f32x2;

__device__ __forceinline__ unsigned short f2bf(float f) {
    unsigned int u = __builtin_bit_cast(unsigned int, f);
    u += 0x7FFFu + ((u >> 16) & 1u);   // RNE
    return (unsigned short)(u >> 16);
}
__device__ __forceinline__ float bf2f(unsigned short s) {
    return __builtin_bit_cast(float, (unsigned int)s << 16);
}

// fp8 e4m3 (OCP) encode/decode
__device__ __forceinline__ unsigned char f2fp8(float v) {
#if __has_builtin(__builtin_amdgcn_cvt_pk_fp8_f32)
    int p = __builtin_amdgcn_cvt_pk_fp8_f32(v, v, 0, false);
    return (unsigned char)(p & 0xFF);
#else
    __hip_fp8_e4m3 q(v);
    return (unsigned char)q.__x;
#endif
}
template <bool HI>
__device__ __forceinline__ f32x2 fp8pair2f(int word) {
#if __has_builtin(__builtin_amdgcn_cvt_pk_f32_fp8)
    return __builtin_amdgcn_cvt_pk_f32_fp8(word, HI);
#else
    f32x2 r;
    __hip_fp8_e4m3 a, b;
    a.__x = (unsigned char)((word >> (HI ? 16 : 0)) & 0xFF);
    b.__x = (unsigned char)((word >> (HI ? 24 : 8)) & 0xFF);
    r.x = (float)a; r.y = (float)b;
    return r;
#endif
}

__device__ __forceinline__ void gload_lds16(const void* g, void* l) {
    __builtin_amdgcn_global_load_lds(
        (const __attribute__((address_space(1))) void*)g,
        (__attribute__((address_space(3))) void*)l, 16, 0, 0);
}

// inline-asm ds_read_b128: opaque to hipcc's alias analysis, so the compiler
// cannot insert its own s_waitcnt vmcnt(0) before LDS reads of
// global_load_lds-written buffers (R5/R11 failure mode). OFF is a literal.
#define DS_READ_B128(dst, addr, OFF) \
    asm volatile("ds_read_b128 %0, %1 offset:" OFF : "=v"(dst) : "v"(addr))

// ---------------- conversions ----------------

__global__ void k_cvt_x(const float* __restrict__ x, unsigned short* __restrict__ xb) {
    size_t e = ((size_t)blockIdx.x * 256 + threadIdx.x) * 8;
    if (e >= (size_t)MPAD * FIN) return;
    bf16x8 o;
    if (e < (size_t)NNODES * FIN) {
        float4 v0 = *(const float4*)(x + e);
        float4 v1 = *(const float4*)(x + e + 4);
        o[0] = f2bf(v0.x); o[1] = f2bf(v0.y); o[2] = f2bf(v0.z); o[3] = f2bf(v0.w);
        o[4] = f2bf(v1.x); o[5] = f2bf(v1.y); o[6] = f2bf(v1.z); o[7] = f2bf(v1.w);
    } else {
        o = (bf16x8)0;
    }
    *(bf16x8*)(xb + e) = o;
}

__global__ void k_cvt_wt(const float* __restrict__ W, unsigned short* __restrict__ Wt, int K) {
    int t = blockIdx.x * 256 + threadIdx.x;
    if (t >= 512 * K) return;
    int n = t / K, k = t - n * K;
    Wt[t] = f2bf(W[(size_t)k * 512 + n]);
}

// ---------------- CSR build ----------------

__global__ void k_deg(const int* __restrict__ dst, int* __restrict__ deg) {
    int e = blockIdx.x * 256 + threadIdx.x;
    if (e < NEDGES) atomicAdd(&deg[dst[e]], 1);
}

__global__ void k_scan(const int* __restrict__ deg, int* __restrict__ off, int* __restrict__ cursor) {
    __shared__ int sh[1024];
    constexpr int CH = (NNODES + 1023) / 1024;
    int t = threadIdx.x;
    int base = t * CH;
    int vals[CH];
    int local = 0;
#pragma unroll
    for (int i = 0; i < CH; ++i) {
        int idx = base + i;
        int v = (idx < NNODES) ? deg[idx] : 0;
        vals[i] = v;
        local += v;
    }
    sh[t] = local;
    __syncthreads();
    for (int o = 1; o < 1024; o <<= 1) {
        int add = (t >= o) ? sh[t - o] : 0;
        __syncthreads();
        sh[t] += add;
        __syncthreads();
    }
    int run = sh[t] - local;
#pragma unroll
    for (int i = 0; i < CH; ++i) {
        int idx = base + i;
        if (idx < NNODES) {
            off[idx] = run;
            cursor[idx] = run;
            run += vals[i];
        }
    }
    if (t == 1023) off[NNODES] = sh[1023];
}

__global__ void k_fill(const int* __restrict__ src, const int* __restrict__ dst,
                       const float* __restrict__ ew, int* __restrict__ cursor,
                       int* __restrict__ csrc, float* __restrict__ cw) {
    int e = blockIdx.x * 256 + threadIdx.x;
    if (e < NEDGES) {
        int p = atomicAdd(&cursor[dst[e]], 1);
        csrc[p] = src[e];
        cw[p] = ew[e];
    }
}

// ---------------- aggregation (gather form) ----------------

__global__ void k_agg128(const unsigned short* __restrict__ xb, const int* __restrict__ off,
                         const int* __restrict__ csrc, const float* __restrict__ cw,
                         unsigned short* __restrict__ out) {
    int node = blockIdx.x * 4 + (threadIdx.x >> 6);
    if (node >= NNODES) return;
    int lane = threadIdx.x & 63;
    float a0 = 0.f, a1 = 0.f;
    int s = off[node], e = off[node + 1];
    for (int k = s; k < e; ++k) {
        int j = csrc[k];
        float w = cw[k];
        unsigned int v = *(const unsigned int*)(xb + (size_t)j * FIN + lane * 2);
        a0 += w * bf2f((unsigned short)(v & 0xFFFF));
        a1 += w * bf2f((unsigned short)(v >> 16));
    }
    unsigned int o = (unsigned int)f2bf(a0) | ((unsigned int)f2bf(a1) << 16);
    *(unsigned int*)(out + (size_t)node * FIN + lane * 2) = o;
}

// conv2 aggregation: gather fp8 h1 rows (512 B/row), fp32 accum, bf16 out.
__global__ void k_agg512(const unsigned char* __restrict__ h8, const int* __restrict__ off,
                         const int* __restrict__ csrc, const float* __restrict__ cw,
                         unsigned short* __restrict__ out) {
    int node = blockIdx.x * 4 + (threadIdx.x >> 6);
    if (node >= NNODES) return;
    int lane = threadIdx.x & 63;
    float acc[8] = {};
    int s = off[node], e = off[node + 1];
    for (int k = s; k < e; ++k) {
        int j = csrc[k];
        float w = cw[k];
        int2 v = *(const int2*)(h8 + (size_t)j * HID + lane * 8);
        f32x2 f01 = fp8pair2f<false>(v.x);
        f32x2 f23 = fp8pair2f<true>(v.x);
        f32x2 f45 = fp8pair2f<false>(v.y);
        f32x2 f67 = fp8pair2f<true>(v.y);
        acc[0] += w * f01.x; acc[1] += w * f01.y;
        acc[2] += w * f23.x; acc[3] += w * f23.y;
        acc[4] += w * f45.x; acc[5] += w * f45.y;
        acc[6] += w * f67.x; acc[7] += w * f67.y;
    }
    bf16x8 o;
#pragma unroll
    for (int q = 0; q < 8; ++q) o[q] = (short)f2bf(acc[q]);
    *(bf16x8*)(out + (size_t)node * HID + lane * 8) = o;
}

// ---------------- dual MFMA GEMM: C = relu(A0@B0 + A1@B1 + bias) ----------------
// 256x256 tile, 512 threads = 8 waves (2M x 4N), wave tile 128x64, (512,2).
// R12: fragment loads are INLINE-ASM ds_read_b128 (opaque to hipcc) so the
// compiler cannot re-insert vmcnt(0) before them -- the R5/R9/R11 serializer.
// Explicit waits only: lgkmcnt(0)+sched_barrier(0) before MFMA (rule #18),
// counted vmcnt(4) + s_barrier at the sub-tile boundary (T4: never vmcnt(0)
// mid-loop). Ring of 4 BK=32 buffers (128KB LDS). Ledger: prologue stages
// s0,s1 (out=8), vmcnt(4) drains s0; iter s issues stage(s+2) (out=8),
// boundary vmcnt(4) drains exactly stage(s+1). stage(s+2) writes buf (s+2)&3,
// whose readers are >=2 barriers in the past. LDS addresses: 32-bit offsets
// (low 32 of generic pointer; gfx9 apertures are 4GB-aligned) + literal
// offset: immediates (rows are 64B -> m*1024B).
// R4-verified 4-slot XOR swizzle (0 bank conflicts), both sides (rule #21).
// GEMM1 (!POOL) epilogue dual-emits C (bf16) + C8 (fp8 e4m3) for the gather.

template <int K, bool POOL>
__global__ __launch_bounds__(512, 2)
void k_mfma_dual(const unsigned short* __restrict__ A0, const unsigned short* __restrict__ B0t,
                 const unsigned short* __restrict__ A1, const unsigned short* __restrict__ B1t,
                 const float* __restrict__ bias,
                 unsigned short* __restrict__ C, unsigned char* __restrict__ C8,
                 const int* __restrict__ batch, float* __restrict__ psum) {
    constexpr int KT = K / 32;       // sub-tiles per matrix
    constexpr int S = 2 * KT;        // total sub-tiles (two matrices)
    __shared__ unsigned short As[4][256 * 32];   // 16KB per buf
    __shared__ unsigned short Bs[4][256 * 32];
    int tid = threadIdx.x;
    int l = tid & 63, w = tid >> 6;
    int wr = w >> 2, wc = w & 3;     // 2M x 4N waves, wave tile 128x64
    int bid = blockIdx.x;
    int row0 = (bid >> 1) * 256;
    int col0 = (bid & 1) * 256;

    int lr = l & 15, hi = l >> 4;
    int pofs = (hi ^ ((lr >> 1) & 3)) * 8;   // swizzled k-slot offset (ushorts)

    const unsigned short* Amat[2] = {A0, A1};
    const unsigned short* Bmat[2] = {B0t, B1t};

    // staging: chunk c: row r=c>>2, slot p=c&3, global slot g = p ^ ((r>>1)&3)
    int c0 = tid, c1 = tid + 512;
    int r0 = c0 >> 2, g0 = (c0 & 3) ^ ((r0 >> 1) & 3);
    int r1 = c1 >> 2, g1 = (c1 & 3) ^ ((r1 >> 1) & 3);

    auto stage_half = [&](int s, int half) {   // 1 A-load + 1 B-load per thread
        int mat = s / KT;
        int k0 = (s - mat * KT) * 32;
        const unsigned short* A = Amat[mat];
        const unsigned short* Bt = Bmat[mat];
        int c = half ? c1 : c0;
        int r = half ? r1 : r0;
        int g = half ? g1 : g0;
        gload_lds16(A + (size_t)(row0 + r) * K + k0 + g * 8, &As[s & 3][c * 8]);
        gload_lds16(Bt + (size_t)(col0 + r) * K + k0 + g * 8, &Bs[s & 3][c * 8]);
    };

    // per-lane LDS byte addresses (32-bit LDS offsets)
    unsigned a_lane = (unsigned)(unsigned long long)&As[0][0]
                    + (unsigned)(((wr * 128 + lr) * 32 + pofs) * 2);
    unsigned b_lane = (unsigned)(unsigned long long)&Bs[0][0]
                    + (unsigned)(((wc * 64 + lr) * 32 + pofs) * 2);

    f32x4 acc[8][4];
#pragma unroll
    for (int m = 0; m < 8; ++m)
#pragma unroll
        for (int n = 0; n < 4; ++n) acc[m][n] = (f32x4)0.f;

    // prologue: stage s0, s1 -> out=8; drain s0 only.
    stage_half(0, 0); stage_half(0, 1);
    stage_half(1, 0); stage_half(1, 1);
    asm volatile("s_waitcnt vmcnt(4)" ::: "memory");
    __builtin_amdgcn_s_barrier();
    __builtin_amdgcn_sched_barrier(0);

    for (int s = 0; s < S; ++s) {
        // ---- issue next-next stage (VMEM; stays in flight across barrier) ----
        if (s + 2 < S) {
            stage_half(s + 2, 0);
            stage_half(s + 2, 1);
        }
        // ---- fragment loads: inline-asm ds_read_b128, rows 64B apart ----
        unsigned ab = a_lane + (unsigned)((s & 3) * (256 * 32 * 2));
        unsigned bb = b_lane + (unsigned)((s & 3) * (256 * 32 * 2));
        bf16x8 af[8], bfr[4];
        DS_READ_B128(af[0], ab, "0");
        DS_READ_B128(af[1], ab, "1024");
        DS_READ_B128(af[2], ab, "2048");
        DS_READ_B128(af[3], ab, "3072");
        DS_READ_B128(af[4], ab, "4096");
        DS_READ_B128(af[5], ab, "5120");
        DS_READ_B128(af[6], ab, "6144");
        DS_READ_B128(af[7], ab, "7168");
        DS_READ_B128(bfr[0], bb, "0");
        DS_READ_B128(bfr[1], bb, "1024");
        DS_READ_B128(bfr[2], bb, "2048");
        DS_READ_B128(bfr[3], bb, "3072");
        asm volatile("s_waitcnt lgkmcnt(0)" ::: "memory");
        __builtin_amdgcn_sched_barrier(0);   // rule #18: keep MFMA below the wait
        // ---- MFMA clusters ----
        __builtin_amdgcn_s_setprio(1);
#pragma unroll
        for (int m = 0; m < 4; ++m)
#pragma unroll
            for (int n = 0; n < 4; ++n)
                acc[m][n] = __builtin_amdgcn_mfma_f32_16x16x32_bf16(af[m], bfr[n], acc[m][n], 0, 0, 0);
        __builtin_amdgcn_s_setprio(0);
        __builtin_amdgcn_s_setprio(1);
#pragma unroll
        for (int m = 0; m < 4; ++m)
#pragma unroll
            for (int n = 0; n < 4; ++n)
                acc[4 + m][n] = __builtin_amdgcn_mfma_f32_16x16x32_bf16(af[4 + m], bfr[n], acc[4 + m][n], 0, 0, 0);
        __builtin_amdgcn_s_setprio(0);
        // ---- boundary: drain stage(s+1) only; keep stage(s+2) in flight ----
        if (s + 2 < S) {
            asm volatile("s_waitcnt vmcnt(4)" ::: "memory");
        } else {
            asm volatile("s_waitcnt vmcnt(0)" ::: "memory");
        }
        if (s + 1 < S) {
            __builtin_amdgcn_s_barrier();
            __builtin_amdgcn_sched_barrier(0);
        }
    }

    // epilogue: C/D layout col = l&15, row = (l>>4)*4 + i
    float bv[4];
#pragma unroll
    for (int n = 0; n < 4; ++n) bv[n] = bias[col0 + wc * 64 + n * 16 + lr];
    int rbase = row0 + wr * 128 + hi * 4;

    if constexpr (!POOL) {
#pragma unroll
        for (int m = 0; m < 8; ++m) {
#pragma unroll
            for (int i = 0; i < 4; ++i) {
                int rr = rbase + m * 16 + i;
                if (rr < NNODES) {
#pragma unroll
                    for (int n = 0; n < 4; ++n) {
                        int col = col0 + wc * 64 + n * 16 + lr;
                        float v = fmaxf(acc[m][n][i] + bv[n], 0.f);
                        C[(size_t)rr * HID + col] = f2bf(v);
                        C8[(size_t)rr * HID + col] = f2fp8(v);
                    }
                }
            }
        }
    } else {
#pragma unroll
        for (int m = 0; m < 8; ++m) {
            int b[4];
#pragma unroll
            for (int i = 0; i < 4; ++i) {
                int rr = rbase + m * 16 + i;
                b[i] = (rr < NNODES) ? batch[rr] : -1;
            }
#pragma unroll
            for (int n = 0; n < 4; ++n) {
                int col = col0 + wc * 64 + n * 16 + lr;
                int cb = -1;
                float run = 0.f;
#pragma unroll
                for (int i = 0; i < 4; ++i) {
                    if (b[i] >= 0) {
                        float v = fmaxf(acc[m][n][i] + bv[n], 0.f);
                        if (b[i] == cb) {
                            run += v;
                        } else {
                            if (cb >= 0) atomicAdd(&psum[(size_t)cb * HID + col], run);
                            cb = b[i];
                            run = v;
                        }
                    }
                }
                if (cb >= 0) atomicAdd(&psum[(size_t)cb * HID + col], run);
            }
        }
    }
}

// ---------------- pooling count (LDS histogram) + MLP head (fp32) ----------------

__global__ void k_cnt(const int* __restrict__ batch, float* __restrict__ cnt) {
    __shared__ int h[NGRAPH];
    int t = threadIdx.x;
    if (t < NGRAPH) h[t] = 0;
    __syncthreads();
    int i = blockIdx.x * 256 + t;
    if (i < NNODES) atomicAdd(&h[batch[i]], 1);
    __syncthreads();
    if (t < NGRAPH && h[t] != 0) atomicAdd(&cnt[t], (float)h[t]);
}

__global__ void k_head(const float* __restrict__ psum, const float* __restrict__ cnt,
                       const float* __restrict__ W1, const float* __restrict__ b1,
                       const float* __restrict__ W2, const float* __restrict__ b2,
                       const float* __restrict__ W3, const float* __restrict__ b3,
                       float* __restrict__ out) {
    __shared__ float pooled[HID];
    __shared__ float o1[64];
    __shared__ float o2[16];
    int g = blockIdx.x, t = threadIdx.x;
    float c = fmaxf(cnt[g], 1.0f);
    for (int k = t; k < HID; k += 64) pooled[k] = psum[(size_t)g * HID + k] / c;
    __syncthreads();
    float a = b1[t];
    for (int k = 0; k < HID; ++k) a += pooled[k] * W1[k * 64 + t];
    o1[t] = fmaxf(a, 0.f);
    __syncthreads();
    if (t < 16) {
        float a2 = b2[t];
        for (int k = 0; k < 64; ++k) a2 += o1[k] * W2[k * 16 + t];
        o2[t] = fmaxf(a2, 0.f);
    }
    __syncthreads();
    if (t == 0) {
        float a3 = b3[0];
        for (int k = 0; k < 16; ++k) a3 += o2[k] * W3[k];
        out[g] = a3;
    }
}

// ---------------- launch ----------------

extern "C" void kernel_launch(void* const* d_in, const int* in_sizes, int n_in,
                              void* d_out, int out_size, void* d_ws, size_t ws_size,
                              hipStream_t stream) {
    const float* x = (const float*)d_in[0];
    const int* ei = (const int*)d_in[1];
    const int* src = ei;
    const int* dst = ei + NEDGES;
    const float* ew = (const float*)d_in[2];
    const int* batch = (const int*)d_in[3];
    const float* Wr1 = (const float*)d_in[4];
    const float* br1 = (const float*)d_in[5];
    const float* Wo1 = (const float*)d_in[6];
    const float* Wr2 = (const float*)d_in[7];
    const float* br2 = (const float*)d_in[8];
    const float* Wo2 = (const float*)d_in[9];
    const float* W1 = (const float*)d_in[10];
    const float* b1 = (const float*)d_in[11];
    const float* W2 = (const float*)d_in[12];
    const float* b2 = (const float*)d_in[13];
    const float* W3 = (const float*)d_in[14];
    const float* b3 = (const float*)d_in[15];
    float* out = (float*)d_out;

    char* ws = (char*)d_ws;
    size_t o = 0;
    auto alloc = [&](size_t bytes) -> void* {
        void* p = ws + o;
        o = (o + bytes + 255) & ~(size_t)255;
        return p;
    };
    int* deg = (int*)alloc((size_t)NNODES * 4);
    int* off = (int*)alloc((size_t)(NNODES + 1) * 4);
    int* cur = (int*)alloc((size_t)NNODES * 4);
    int* csrc = (int*)alloc((size_t)NEDGES * 4);
    float* cw = (float*)alloc((size_t)NEDGES * 4);
    unsigned short* xb = (unsigned short*)alloc((size_t)MPAD * FIN * 2);
    unsigned short* agg1 = (unsigned short*)alloc((size_t)MPAD * FIN * 2);
    unsigned short* h1 = (unsigned short*)alloc((size_t)MPAD * HID * 2);
    unsigned char* h1f8 = (unsigned char*)alloc((size_t)MPAD * HID);
    unsigned short* agg2 = (unsigned short*)alloc((size_t)MPAD * HID * 2);
    unsigned short* Wr1t = (unsigned short*)alloc((size_t)512 * FIN * 2);
    unsigned short* Wo1t = (unsigned short*)alloc((size_t)512 * FIN * 2);
    unsigned short* Wr2t = (unsigned short*)alloc((size_t)512 * HID * 2);
    unsigned short* Wo2t = (unsigned short*)alloc((size_t)512 * HID * 2);
    float* psum = (float*)alloc((size_t)NGRAPH * HID * 4);
    float* cnt = (float*)alloc((size_t)NGRAPH * 4);

    hipMemsetAsync(deg, 0, (size_t)NNODES * 4, stream);
    hipMemsetAsync(psum, 0, (size_t)NGRAPH * HID * 4, stream);
    hipMemsetAsync(cnt, 0, (size_t)NGRAPH * 4, stream);

    // conversions
    k_cvt_x<<<((MPAD * FIN / 8) + 255) / 256, 256, 0, stream>>>(x, xb);
    k_cvt_wt<<<(512 * FIN + 255) / 256, 256, 0, stream>>>(Wr1, Wr1t, FIN);
    k_cvt_wt<<<(512 * FIN + 255) / 256, 256, 0, stream>>>(Wo1, Wo1t, FIN);
    k_cvt_wt<<<(512 * HID + 255) / 256, 256, 0, stream>>>(Wr2, Wr2t, HID);
    k_cvt_wt<<<(512 * HID + 255) / 256, 256, 0, stream>>>(Wo2, Wo2t, HID);

    // CSR
    k_deg<<<(NEDGES + 255) / 256, 256, 0, stream>>>(dst, deg);
    k_scan<<<1, 1024, 0, stream>>>(deg, off, cur);
    k_fill<<<(NEDGES + 255) / 256, 256, 0, stream>>>(src, dst, ew, cur, csrc, cw);

    // layer 1
    k_agg128<<<(NNODES + 3) / 4, 256, 0, stream>>>(xb, off, csrc, cw, agg1);
    int nblk = (MPAD / 256) * 2;   // col in low bit of block id
    k_mfma_dual<FIN, false><<<nblk, 512, 0, stream>>>(agg1, Wr1t, xb, Wo1t, br1, h1, h1f8, nullptr, nullptr);

    // layer 2 (+ fused mean-pool numerator)
    k_agg512<<<(NNODES + 3) / 4, 256, 0, stream>>>(h1f8, off, csrc, cw, agg2);
    k_cnt<<<(NNODES + 255) / 256, 256, 0, stream>>>(batch, cnt);
    k_mfma_dual<HID, true><<<nblk, 512, 0, stream>>>(agg2, Wr2t, h1, Wo2t, br2, nullptr, nullptr, batch, psum);

    // head
    k_head<<<NGRAPH, 64, 0, stream>>>(psum, cnt, W1, b1, W2, b2, W3, b3, out);
}

// Round 13
// 379.750 us; speedup vs baseline: 1.1968x; 1.1968x over previous
//
#include <hip/hip_runtime.h>
#include <hip/hip_bf16.h>
#include <hip/hip_fp8.h>

#define NNODES 40000
#define MPAD   40000   // 250 * 160 -- exact, no padding
#define NEDGES 640000
#define FIN    128
#define HID    512
#define NGRAPH 64
#define BM     160     // 40000 = 250*160; grid 500 -> 98% CU utilization

typedef __attribute__((ext_vector_type(8))) short bf16x8;
typedef __attribute__((ext_vector_type(4))) float f32x4;
typedef __attribute__((ext_vector_type(2))) float f32x2;

__device__ __forceinline__ unsigned short f2bf(float f) {
    unsigned int u = __builtin_bit_cast(unsigned int, f);
    u += 0x7FFFu + ((u >> 16) & 1u);   // RNE
    return (unsigned short)(u >> 16);
}
__device__ __forceinline__ float bf2f(unsigned short s) {
    return __builtin_bit_cast(float, (unsigned int)s << 16);
}

// fp8 e4m3 (OCP) encode/decode
__device__ __forceinline__ unsigned char f2fp8(float v) {
#if __has_builtin(__builtin_amdgcn_cvt_pk_fp8_f32)
    int p = __builtin_amdgcn_cvt_pk_fp8_f32(v, v, 0, false);
    return (unsigned char)(p & 0xFF);
#else
    __hip_fp8_e4m3 q(v);
    return (unsigned char)q.__x;
#endif
}
template <bool HI>
__device__ __forceinline__ f32x2 fp8pair2f(int word) {
#if __has_builtin(__builtin_amdgcn_cvt_pk_f32_fp8)
    return __builtin_amdgcn_cvt_pk_f32_fp8(word, HI);
#else
    f32x2 r;
    __hip_fp8_e4m3 a, b;
    a.__x = (unsigned char)((word >> (HI ? 16 : 0)) & 0xFF);
    b.__x = (unsigned char)((word >> (HI ? 24 : 8)) & 0xFF);
    r.x = (float)a; r.y = (float)b;
    return r;
#endif
}

__device__ __forceinline__ void gload_lds16(const void* g, void* l) {
    __builtin_amdgcn_global_load_lds(
        (const __attribute__((address_space(1))) void*)g,
        (__attribute__((address_space(3))) void*)l, 16, 0, 0);
}
__device__ __forceinline__ void gload_lds4(const void* g, void* l) {
    __builtin_amdgcn_global_load_lds(
        (const __attribute__((address_space(1))) void*)g,
        (__attribute__((address_space(3))) void*)l, 4, 0, 0);
}

// inline-asm ds_read_b128 (kept from R12; opaque to hipcc alias analysis)
#define DS_READ_B128(dst, addr, OFF) \
    asm volatile("ds_read_b128 %0, %1 offset:" OFF : "=v"(dst) : "v"(addr))

// ---------------- conversions ----------------

__global__ void k_cvt_x(const float* __restrict__ x, unsigned short* __restrict__ xb) {
    size_t e = ((size_t)blockIdx.x * 256 + threadIdx.x) * 8;
    if (e >= (size_t)MPAD * FIN) return;
    float4 v0 = *(const float4*)(x + e);
    float4 v1 = *(const float4*)(x + e + 4);
    bf16x8 o;
    o[0] = f2bf(v0.x); o[1] = f2bf(v0.y); o[2] = f2bf(v0.z); o[3] = f2bf(v0.w);
    o[4] = f2bf(v1.x); o[5] = f2bf(v1.y); o[6] = f2bf(v1.z); o[7] = f2bf(v1.w);
    *(bf16x8*)(xb + e) = o;
}

__global__ void k_cvt_wt(const float* __restrict__ W, unsigned short* __restrict__ Wt, int K) {
    int t = blockIdx.x * 256 + threadIdx.x;
    if (t >= 512 * K) return;
    int n = t / K, k = t - n * K;
    Wt[t] = f2bf(W[(size_t)k * 512 + n]);
}

// ---------------- CSR build ----------------

__global__ void k_deg(const int* __restrict__ dst, int* __restrict__ deg) {
    int e = blockIdx.x * 256 + threadIdx.x;
    if (e < NEDGES) atomicAdd(&deg[dst[e]], 1);
}

__global__ void k_scan(const int* __restrict__ deg, int* __restrict__ off, int* __restrict__ cursor) {
    __shared__ int sh[1024];
    constexpr int CH = (NNODES + 1023) / 1024;
    int t = threadIdx.x;
    int base = t * CH;
    int vals[CH];
    int local = 0;
#pragma unroll
    for (int i = 0; i < CH; ++i) {
        int idx = base + i;
        int v = (idx < NNODES) ? deg[idx] : 0;
        vals[i] = v;
        local += v;
    }
    sh[t] = local;
    __syncthreads();
    for (int o = 1; o < 1024; o <<= 1) {
        int add = (t >= o) ? sh[t - o] : 0;
        __syncthreads();
        sh[t] += add;
        __syncthreads();
    }
    int run = sh[t] - local;
#pragma unroll
    for (int i = 0; i < CH; ++i) {
        int idx = base + i;
        if (idx < NNODES) {
            off[idx] = run;
            cursor[idx] = run;
            run += vals[i];
        }
    }
    if (t == 1023) off[NNODES] = sh[1023];
}

__global__ void k_fill(const int* __restrict__ src, const int* __restrict__ dst,
                       const float* __restrict__ ew, int* __restrict__ cursor,
                       int* __restrict__ csrc, float* __restrict__ cw) {
    int e = blockIdx.x * 256 + threadIdx.x;
    if (e < NEDGES) {
        int p = atomicAdd(&cursor[dst[e]], 1);
        csrc[p] = src[e];
        cw[p] = ew[e];
    }
}

// ---------------- aggregation (gather form, 4-wide edge unroll for MLP) ----------------

__global__ void k_agg128(const unsigned short* __restrict__ xb, const int* __restrict__ off,
                         const int* __restrict__ csrc, const float* __restrict__ cw,
                         unsigned short* __restrict__ out) {
    int node = blockIdx.x * 4 + (threadIdx.x >> 6);
    if (node >= NNODES) return;
    int lane = threadIdx.x & 63;
    float a0 = 0.f, a1 = 0.f;
    int s = off[node], e = off[node + 1];
    int k = s;
    for (; k + 3 < e; k += 4) {
        int j0 = csrc[k], j1 = csrc[k + 1], j2 = csrc[k + 2], j3 = csrc[k + 3];
        float w0 = cw[k], w1 = cw[k + 1], w2 = cw[k + 2], w3 = cw[k + 3];
        unsigned int v0 = *(const unsigned int*)(xb + (size_t)j0 * FIN + lane * 2);
        unsigned int v1 = *(const unsigned int*)(xb + (size_t)j1 * FIN + lane * 2);
        unsigned int v2 = *(const unsigned int*)(xb + (size_t)j2 * FIN + lane * 2);
        unsigned int v3 = *(const unsigned int*)(xb + (size_t)j3 * FIN + lane * 2);
        a0 += w0 * bf2f((unsigned short)(v0 & 0xFFFF)); a1 += w0 * bf2f((unsigned short)(v0 >> 16));
        a0 += w1 * bf2f((unsigned short)(v1 & 0xFFFF)); a1 += w1 * bf2f((unsigned short)(v1 >> 16));
        a0 += w2 * bf2f((unsigned short)(v2 & 0xFFFF)); a1 += w2 * bf2f((unsigned short)(v2 >> 16));
        a0 += w3 * bf2f((unsigned short)(v3 & 0xFFFF)); a1 += w3 * bf2f((unsigned short)(v3 >> 16));
    }
    for (; k < e; ++k) {
        int j = csrc[k];
        float w = cw[k];
        unsigned int v = *(const unsigned int*)(xb + (size_t)j * FIN + lane * 2);
        a0 += w * bf2f((unsigned short)(v & 0xFFFF));
        a1 += w * bf2f((unsigned short)(v >> 16));
    }
    unsigned int o = (unsigned int)f2bf(a0) | ((unsigned int)f2bf(a1) << 16);
    *(unsigned int*)(out + (size_t)node * FIN + lane * 2) = o;
}

__global__ void k_agg512(const unsigned char* __restrict__ h8, const int* __restrict__ off,
                         const int* __restrict__ csrc, const float* __restrict__ cw,
                         unsigned short* __restrict__ out) {
    int node = blockIdx.x * 4 + (threadIdx.x >> 6);
    if (node >= NNODES) return;
    int lane = threadIdx.x & 63;
    float acc[8] = {};
    int s = off[node], e = off[node + 1];
    auto accum = [&](int2 v, float w) {
        f32x2 f01 = fp8pair2f<false>(v.x);
        f32x2 f23 = fp8pair2f<true>(v.x);
        f32x2 f45 = fp8pair2f<false>(v.y);
        f32x2 f67 = fp8pair2f<true>(v.y);
        acc[0] += w * f01.x; acc[1] += w * f01.y;
        acc[2] += w * f23.x; acc[3] += w * f23.y;
        acc[4] += w * f45.x; acc[5] += w * f45.y;
        acc[6] += w * f67.x; acc[7] += w * f67.y;
    };
    int k = s;
    for (; k + 3 < e; k += 4) {
        int j0 = csrc[k], j1 = csrc[k + 1], j2 = csrc[k + 2], j3 = csrc[k + 3];
        float w0 = cw[k], w1 = cw[k + 1], w2 = cw[k + 2], w3 = cw[k + 3];
        int2 v0 = *(const int2*)(h8 + (size_t)j0 * HID + lane * 8);
        int2 v1 = *(const int2*)(h8 + (size_t)j1 * HID + lane * 8);
        int2 v2 = *(const int2*)(h8 + (size_t)j2 * HID + lane * 8);
        int2 v3 = *(const int2*)(h8 + (size_t)j3 * HID + lane * 8);
        accum(v0, w0); accum(v1, w1); accum(v2, w2); accum(v3, w3);
    }
    for (; k < e; ++k) {
        int2 v = *(const int2*)(h8 + (size_t)csrc[k] * HID + lane * 8);
        accum(v, cw[k]);
    }
    bf16x8 o;
#pragma unroll
    for (int q = 0; q < 8; ++q) o[q] = (short)f2bf(acc[q]);
    *(bf16x8*)(out + (size_t)node * HID + lane * 8) = o;
}

// ---------------- dual MFMA GEMM: C = relu(A0@B0 + A1@B1 + bias) ----------------
// R13: BM=160 (40000 = 250*160 exact) -> grid 500 -> <=2 blocks/CU -> 98% CU
// utilization (vs 314 blocks = 61%, the Occupancy-15% tail). 512 threads =
// 8 waves (2M x 4N), wave tile 80x64, acc[5][4], (512,2) -- R8: never raise
// the wave/EU bound. Ring of 4 BK=32 buffers; R9-verified counted-vmcnt
// boundary. Staging per sub-tile: B = 1024 16B-chunks (2/thread, 16B gload),
// A = 2560 4B-words (5/thread, 4B gload -- 160x32x2B isn't 16B-uniform over
// 512 threads). Uniform 7 VMEM/thread/stage -> ledger: prologue stages s0,s1
// (14 out), vmcnt(7) drains s0; iter issues stage(s+2) (14 out), boundary
// vmcnt(7) drains exactly stage(s+1); never vmcnt(0) mid-loop.
// Slot-XOR swizzle both sides (rule #21), verified 0 conflicts; read-side
// identity (R>>1)&3 == (lr>>1)&3 holds since 80 = 5*16.
// GEMM1 (!POOL) epilogue dual-emits C (bf16) + C8 (fp8 e4m3) for the gather.

template <int K, bool POOL>
__global__ __launch_bounds__(512, 2)
void k_mfma_dual(const unsigned short* __restrict__ A0, const unsigned short* __restrict__ B0t,
                 const unsigned short* __restrict__ A1, const unsigned short* __restrict__ B1t,
                 const float* __restrict__ bias,
                 unsigned short* __restrict__ C, unsigned char* __restrict__ C8,
                 const int* __restrict__ batch, float* __restrict__ psum) {
    constexpr int KT = K / 32;       // sub-tiles per matrix
    constexpr int S = 2 * KT;        // total sub-tiles (two matrices)
    __shared__ unsigned short As[4][BM * 32];    // 10 KB per buf
    __shared__ unsigned short Bs[4][256 * 32];   // 16 KB per buf
    int tid = threadIdx.x;
    int l = tid & 63, w = tid >> 6;
    int wr = w >> 2, wc = w & 3;     // 2M x 4N waves, wave tile 80x64
    int bid = blockIdx.x;
    int row0 = (bid >> 1) * BM;
    int col0 = (bid & 1) * 256;

    int lr = l & 15, hi = l >> 4;
    int pofs = (hi ^ ((lr >> 1) & 3)) * 8;   // swizzled k-slot offset (ushorts)

    const unsigned short* Amat[2] = {A0, A1};
    const unsigned short* Bmat[2] = {B0t, B1t};

    // B staging chunk geometry (16B chunks): c: row r=c>>2, slot p=c&3,
    // global slot g = p ^ ((r>>1)&3); LDS dest linear at c*16B.
    int bc0 = tid, bc1 = tid + 512;
    int br0 = bc0 >> 2, bg0 = (bc0 & 3) ^ ((br0 >> 1) & 3);
    int br1 = bc1 >> 2, bg1 = (bc1 & 3) ^ ((br1 >> 1) & 3);

    auto stage = [&](int s) {   // 7 VMEM/thread: 2x16B B + 5x4B A
        int mat = s / KT;
        int k0 = (s - mat * KT) * 32;
        const unsigned short* A = Amat[mat];
        const unsigned short* Bt = Bmat[mat];
        gload_lds16(Bt + (size_t)(col0 + br0) * K + k0 + bg0 * 8, &Bs[s & 3][bc0 * 8]);
        gload_lds16(Bt + (size_t)(col0 + br1) * K + k0 + bg1 * 8, &Bs[s & 3][bc1 * 8]);
#pragma unroll
        for (int q = 0; q < 5; ++q) {
            int c = tid + q * 512;            // 4B word id, 0..2559
            int r = c >> 4;                   // 16 words (64B) per row
            int g = ((c >> 2) & 3) ^ ((r >> 1) & 3);
            int u = c & 3;                    // word within 16B slot
            gload_lds4(A + (size_t)(row0 + r) * K + k0 + g * 8 + u * 2, &As[s & 3][c * 2]);
        }
    };

    // per-lane LDS byte addresses (32-bit LDS offsets)
    unsigned a_lane = (unsigned)(unsigned long long)&As[0][0]
                    + (unsigned)(((wr * 80 + lr) * 32 + pofs) * 2);
    unsigned b_lane = (unsigned)(unsigned long long)&Bs[0][0]
                    + (unsigned)(((wc * 64 + lr) * 32 + pofs) * 2);

    f32x4 acc[5][4];
#pragma unroll
    for (int m = 0; m < 5; ++m)
#pragma unroll
        for (int n = 0; n < 4; ++n) acc[m][n] = (f32x4)0.f;

    // prologue: stage s0, s1 -> 14 outstanding; drain s0 only.
    stage(0);
    stage(1);
    asm volatile("s_waitcnt vmcnt(7)" ::: "memory");
    __builtin_amdgcn_s_barrier();
    __builtin_amdgcn_sched_barrier(0);

    for (int s = 0; s < S; ++s) {
        if (s + 2 < S) stage(s + 2);
        unsigned ab = a_lane + (unsigned)((s & 3) * (BM * 32 * 2));
        unsigned bb = b_lane + (unsigned)((s & 3) * (256 * 32 * 2));
        bf16x8 af[5], bfr[4];
        DS_READ_B128(af[0], ab, "0");
        DS_READ_B128(af[1], ab, "1024");
        DS_READ_B128(af[2], ab, "2048");
        DS_READ_B128(af[3], ab, "3072");
        DS_READ_B128(af[4], ab, "4096");
        DS_READ_B128(bfr[0], bb, "0");
        DS_READ_B128(bfr[1], bb, "1024");
        DS_READ_B128(bfr[2], bb, "2048");
        DS_READ_B128(bfr[3], bb, "3072");
        asm volatile("s_waitcnt lgkmcnt(0)" ::: "memory");
        __builtin_amdgcn_sched_barrier(0);   // rule #18
        __builtin_amdgcn_s_setprio(1);
#pragma unroll
        for (int m = 0; m < 3; ++m)
#pragma unroll
            for (int n = 0; n < 4; ++n)
                acc[m][n] = __builtin_amdgcn_mfma_f32_16x16x32_bf16(af[m], bfr[n], acc[m][n], 0, 0, 0);
        __builtin_amdgcn_s_setprio(0);
        __builtin_amdgcn_s_setprio(1);
#pragma unroll
        for (int m = 3; m < 5; ++m)
#pragma unroll
            for (int n = 0; n < 4; ++n)
                acc[m][n] = __builtin_amdgcn_mfma_f32_16x16x32_bf16(af[m], bfr[n], acc[m][n], 0, 0, 0);
        __builtin_amdgcn_s_setprio(0);
        // boundary: drain stage(s+1) only; keep stage(s+2) in flight
        if (s + 2 < S) {
            asm volatile("s_waitcnt vmcnt(7)" ::: "memory");
        } else {
            asm volatile("s_waitcnt vmcnt(0)" ::: "memory");
        }
        if (s + 1 < S) {
            __builtin_amdgcn_s_barrier();
            __builtin_amdgcn_sched_barrier(0);
        }
    }

    // epilogue: C/D layout col = l&15, row = (l>>4)*4 + i
    float bv[4];
#pragma unroll
    for (int n = 0; n < 4; ++n) bv[n] = bias[col0 + wc * 64 + n * 16 + lr];
    int rbase = row0 + wr * 80 + hi * 4;

    if constexpr (!POOL) {
#pragma unroll
        for (int m = 0; m < 5; ++m) {
#pragma unroll
            for (int i = 0; i < 4; ++i) {
                int rr = rbase + m * 16 + i;
                if (rr < NNODES) {
#pragma unroll
                    for (int n = 0; n < 4; ++n) {
                        int col = col0 + wc * 64 + n * 16 + lr;
                        float v = fmaxf(acc[m][n][i] + bv[n], 0.f);
                        C[(size_t)rr * HID + col] = f2bf(v);
                        C8[(size_t)rr * HID + col] = f2fp8(v);
                    }
                }
            }
        }
    } else {
#pragma unroll
        for (int m = 0; m < 5; ++m) {
            int b[4];
#pragma unroll
            for (int i = 0; i < 4; ++i) {
                int rr = rbase + m * 16 + i;
                b[i] = (rr < NNODES) ? batch[rr] : -1;
            }
#pragma unroll
            for (int n = 0; n < 4; ++n) {
                int col = col0 + wc * 64 + n * 16 + lr;
                int cb = -1;
                float run = 0.f;
#pragma unroll
                for (int i = 0; i < 4; ++i) {
                    if (b[i] >= 0) {
                        float v = fmaxf(acc[m][n][i] + bv[n], 0.f);
                        if (b[i] == cb) {
                            run += v;
                        } else {
                            if (cb >= 0) atomicAdd(&psum[(size_t)cb * HID + col], run);
                            cb = b[i];
                            run = v;
                        }
                    }
                }
                if (cb >= 0) atomicAdd(&psum[(size_t)cb * HID + col], run);
            }
        }
    }
}

// ---------------- pooling count (LDS histogram) + MLP head (fp32) ----------------

__global__ void k_cnt(const int* __restrict__ batch, float* __restrict__ cnt) {
    __shared__ int h[NGRAPH];
    int t = threadIdx.x;
    if (t < NGRAPH) h[t] = 0;
    __syncthreads();
    int i = blockIdx.x * 256 + t;
    if (i < NNODES) atomicAdd(&h[batch[i]], 1);
    __syncthreads();
    if (t < NGRAPH && h[t] != 0) atomicAdd(&cnt[t], (float)h[t]);
}

__global__ void k_head(const float* __restrict__ psum, const float* __restrict__ cnt,
                       const float* __restrict__ W1, const float* __restrict__ b1,
                       const float* __restrict__ W2, const float* __restrict__ b2,
                       const float* __restrict__ W3, const float* __restrict__ b3,
                       float* __restrict__ out) {
    __shared__ float pooled[HID];
    __shared__ float o1[64];
    __shared__ float o2[16];
    int g = blockIdx.x, t = threadIdx.x;
    float c = fmaxf(cnt[g], 1.0f);
    for (int k = t; k < HID; k += 64) pooled[k] = psum[(size_t)g * HID + k] / c;
    __syncthreads();
    float a = b1[t];
    for (int k = 0; k < HID; ++k) a += pooled[k] * W1[k * 64 + t];
    o1[t] = fmaxf(a, 0.f);
    __syncthreads();
    if (t < 16) {
        float a2 = b2[t];
        for (int k = 0; k < 64; ++k) a2 += o1[k] * W2[k * 16 + t];
        o2[t] = fmaxf(a2, 0.f);
    }
    __syncthreads();
    if (t == 0) {
        float a3 = b3[0];
        for (int k = 0; k < 16; ++k) a3 += o2[k] * W3[k];
        out[g] = a3;
    }
}

// ---------------- launch ----------------

extern "C" void kernel_launch(void* const* d_in, const int* in_sizes, int n_in,
                              void* d_out, int out_size, void* d_ws, size_t ws_size,
                              hipStream_t stream) {
    const float* x = (const float*)d_in[0];
    const int* ei = (const int*)d_in[1];
    const int* src = ei;
    const int* dst = ei + NEDGES;
    const float* ew = (const float*)d_in[2];
    const int* batch = (const int*)d_in[3];
    const float* Wr1 = (const float*)d_in[4];
    const float* br1 = (const float*)d_in[5];
    const float* Wo1 = (const float*)d_in[6];
    const float* Wr2 = (const float*)d_in[7];
    const float* br2 = (const float*)d_in[8];
    const float* Wo2 = (const float*)d_in[9];
    const float* W1 = (const float*)d_in[10];
    const float* b1 = (const float*)d_in[11];
    const float* W2 = (const float*)d_in[12];
    const float* b2 = (const float*)d_in[13];
    const float* W3 = (const float*)d_in[14];
    const float* b3 = (const float*)d_in[15];
    float* out = (float*)d_out;

    char* ws = (char*)d_ws;
    size_t o = 0;
    auto alloc = [&](size_t bytes) -> void* {
        void* p = ws + o;
        o = (o + bytes + 255) & ~(size_t)255;
        return p;
    };
    int* deg = (int*)alloc((size_t)NNODES * 4);
    int* off = (int*)alloc((size_t)(NNODES + 1) * 4);
    int* cur = (int*)alloc((size_t)NNODES * 4);
    int* csrc = (int*)alloc((size_t)NEDGES * 4);
    float* cw = (float*)alloc((size_t)NEDGES * 4);
    unsigned short* xb = (unsigned short*)alloc((size_t)MPAD * FIN * 2);
    unsigned short* agg1 = (unsigned short*)alloc((size_t)MPAD * FIN * 2);
    unsigned short* h1 = (unsigned short*)alloc((size_t)MPAD * HID * 2);
    unsigned char* h1f8 = (unsigned char*)alloc((size_t)MPAD * HID);
    unsigned short* agg2 = (unsigned short*)alloc((size_t)MPAD * HID * 2);
    unsigned short* Wr1t = (unsigned short*)alloc((size_t)512 * FIN * 2);
    unsigned short* Wo1t = (unsigned short*)alloc((size_t)512 * FIN * 2);
    unsigned short* Wr2t = (unsigned short*)alloc((size_t)512 * HID * 2);
    unsigned short* Wo2t = (unsigned short*)alloc((size_t)512 * HID * 2);
    float* psum = (float*)alloc((size_t)NGRAPH * HID * 4);
    float* cnt = (float*)alloc((size_t)NGRAPH * 4);

    hipMemsetAsync(deg, 0, (size_t)NNODES * 4, stream);
    hipMemsetAsync(psum, 0, (size_t)NGRAPH * HID * 4, stream);
    hipMemsetAsync(cnt, 0, (size_t)NGRAPH * 4, stream);

    // conversions
    k_cvt_x<<<((MPAD * FIN / 8) + 255) / 256, 256, 0, stream>>>(x, xb);
    k_cvt_wt<<<(512 * FIN + 255) / 256, 256, 0, stream>>>(Wr1, Wr1t, FIN);
    k_cvt_wt<<<(512 * FIN + 255) / 256, 256, 0, stream>>>(Wo1, Wo1t, FIN);
    k_cvt_wt<<<(512 * HID + 255) / 256, 256, 0, stream>>>(Wr2, Wr2t, HID);
    k_cvt_wt<<<(512 * HID + 255) / 256, 256, 0, stream>>>(Wo2, Wo2t, HID);

    // CSR
    k_deg<<<(NEDGES + 255) / 256, 256, 0, stream>>>(dst, deg);
    k_scan<<<1, 1024, 0, stream>>>(deg, off, cur);
    k_fill<<<(NEDGES + 255) / 256, 256, 0, stream>>>(src, dst, ew, cur, csrc, cw);

    // layer 1
    k_agg128<<<(NNODES + 3) / 4, 256, 0, stream>>>(xb, off, csrc, cw, agg1);
    int nblk = (MPAD / BM) * 2;   // 500 blocks; col in low bit
    k_mfma_dual<FIN, false><<<nblk, 512, 0, stream>>>(agg1, Wr1t, xb, Wo1t, br1, h1, h1f8, nullptr, nullptr);

    // layer 2 (+ fused mean-pool numerator)
    k_agg512<<<(NNODES + 3) / 4, 256, 0, stream>>>(h1f8, off, csrc, cw, agg2);
    k_cnt<<<(NNODES + 255) / 256, 256, 0, stream>>>(batch, cnt);
    k_mfma_dual<HID, true><<<nblk, 512, 0, stream>>>(agg2, Wr2t, h1, Wo2t, br2, nullptr, nullptr, batch, psum);

    // head
    k_head<<<NGRAPH, 64, 0, stream>>>(psum, cnt, W1, b1, W2, b2, W3, b3, out);
}

// Round 14
// 377.699 us; speedup vs baseline: 1.2033x; 1.0054x over previous
//
#include <hip/hip_runtime.h>
#include <hip/hip_bf16.h>
#include <hip/hip_fp8.h>

#define NNODES 40000
#define MPAD   40000   // 250 * 160 -- exact, no padding
#define NEDGES 640000
#define FIN    128
#define HID    512
#define NGRAPH 64
#define BM     160     // 40000 = 250*160; grid 500

typedef __attribute__((ext_vector_type(8))) short bf16x8;
typedef __attribute__((ext_vector_type(4))) float f32x4;
typedef __attribute__((ext_vector_type(2))) float f32x2;

__device__ __forceinline__ unsigned short f2bf(float f) {
    unsigned int u = __builtin_bit_cast(unsigned int, f);
    u += 0x7FFFu + ((u >> 16) & 1u);   // RNE
    return (unsigned short)(u >> 16);
}
__device__ __forceinline__ float bf2f(unsigned short s) {
    return __builtin_bit_cast(float, (unsigned int)s << 16);
}

// fp8 e4m3 (OCP) encode/decode
__device__ __forceinline__ unsigned char f2fp8(float v) {
#if __has_builtin(__builtin_amdgcn_cvt_pk_fp8_f32)
    int p = __builtin_amdgcn_cvt_pk_fp8_f32(v, v, 0, false);
    return (unsigned char)(p & 0xFF);
#else
    __hip_fp8_e4m3 q(v);
    return (unsigned char)q.__x;
#endif
}
template <bool HI>
__device__ __forceinline__ f32x2 fp8pair2f(int word) {
#if __has_builtin(__builtin_amdgcn_cvt_pk_f32_fp8)
    return __builtin_amdgcn_cvt_pk_f32_fp8(word, HI);
#else
    f32x2 r;
    __hip_fp8_e4m3 a, b;
    a.__x = (unsigned char)((word >> (HI ? 16 : 0)) & 0xFF);
    b.__x = (unsigned char)((word >> (HI ? 24 : 8)) & 0xFF);
    r.x = (float)a; r.y = (float)b;
    return r;
#endif
}

__device__ __forceinline__ void gload_lds16(const void* g, void* l) {
    __builtin_amdgcn_global_load_lds(
        (const __attribute__((address_space(1))) void*)g,
        (__attribute__((address_space(3))) void*)l, 16, 0, 0);
}
__device__ __forceinline__ void gload_lds4(const void* g, void* l) {
    __builtin_amdgcn_global_load_lds(
        (const __attribute__((address_space(1))) void*)g,
        (__attribute__((address_space(3))) void*)l, 4, 0, 0);
}

// inline-asm ds_read_b128 (opaque to hipcc alias analysis)
#define DS_READ_B128(dst, addr, OFF) \
    asm volatile("ds_read_b128 %0, %1 offset:" OFF : "=v"(dst) : "v"(addr))

// ---------------- conversions ----------------

__global__ void k_cvt_x(const float* __restrict__ x, unsigned short* __restrict__ xb) {
    size_t e = ((size_t)blockIdx.x * 256 + threadIdx.x) * 8;
    if (e >= (size_t)MPAD * FIN) return;
    float4 v0 = *(const float4*)(x + e);
    float4 v1 = *(const float4*)(x + e + 4);
    bf16x8 o;
    o[0] = f2bf(v0.x); o[1] = f2bf(v0.y); o[2] = f2bf(v0.z); o[3] = f2bf(v0.w);
    o[4] = f2bf(v1.x); o[5] = f2bf(v1.y); o[6] = f2bf(v1.z); o[7] = f2bf(v1.w);
    *(bf16x8*)(xb + e) = o;
}

__global__ void k_cvt_wt(const float* __restrict__ W, unsigned short* __restrict__ Wt, int K) {
    int t = blockIdx.x * 256 + threadIdx.x;
    if (t >= 512 * K) return;
    int n = t / K, k = t - n * K;
    Wt[t] = f2bf(W[(size_t)k * 512 + n]);
}

// ---------------- CSR build ----------------

__global__ void k_deg(const int* __restrict__ dst, int* __restrict__ deg) {
    int e = blockIdx.x * 256 + threadIdx.x;
    if (e < NEDGES) atomicAdd(&deg[dst[e]], 1);
}

__global__ void k_scan(const int* __restrict__ deg, int* __restrict__ off, int* __restrict__ cursor) {
    __shared__ int sh[1024];
    constexpr int CH = (NNODES + 1023) / 1024;
    int t = threadIdx.x;
    int base = t * CH;
    int vals[CH];
    int local = 0;
#pragma unroll
    for (int i = 0; i < CH; ++i) {
        int idx = base + i;
        int v = (idx < NNODES) ? deg[idx] : 0;
        vals[i] = v;
        local += v;
    }
    sh[t] = local;
    __syncthreads();
    for (int o = 1; o < 1024; o <<= 1) {
        int add = (t >= o) ? sh[t - o] : 0;
        __syncthreads();
        sh[t] += add;
        __syncthreads();
    }
    int run = sh[t] - local;
#pragma unroll
    for (int i = 0; i < CH; ++i) {
        int idx = base + i;
        if (idx < NNODES) {
            off[idx] = run;
            cursor[idx] = run;
            run += vals[i];
        }
    }
    if (t == 1023) off[NNODES] = sh[1023];
}

__global__ void k_fill(const int* __restrict__ src, const int* __restrict__ dst,
                       const float* __restrict__ ew, int* __restrict__ cursor,
                       int* __restrict__ csrc, float* __restrict__ cw) {
    int e = blockIdx.x * 256 + threadIdx.x;
    if (e < NEDGES) {
        int p = atomicAdd(&cursor[dst[e]], 1);
        csrc[p] = src[e];
        cw[p] = ew[e];
    }
}

// ---------------- aggregation (gather form, 4-wide edge unroll) ----------------

__global__ void k_agg128(const unsigned short* __restrict__ xb, const int* __restrict__ off,
                         const int* __restrict__ csrc, const float* __restrict__ cw,
                         unsigned short* __restrict__ out) {
    int node = blockIdx.x * 4 + (threadIdx.x >> 6);
    if (node >= NNODES) return;
    int lane = threadIdx.x & 63;
    float a0 = 0.f, a1 = 0.f;
    int s = off[node], e = off[node + 1];
    int k = s;
    for (; k + 3 < e; k += 4) {
        int j0 = csrc[k], j1 = csrc[k + 1], j2 = csrc[k + 2], j3 = csrc[k + 3];
        float w0 = cw[k], w1 = cw[k + 1], w2 = cw[k + 2], w3 = cw[k + 3];
        unsigned int v0 = *(const unsigned int*)(xb + (size_t)j0 * FIN + lane * 2);
        unsigned int v1 = *(const unsigned int*)(xb + (size_t)j1 * FIN + lane * 2);
        unsigned int v2 = *(const unsigned int*)(xb + (size_t)j2 * FIN + lane * 2);
        unsigned int v3 = *(const unsigned int*)(xb + (size_t)j3 * FIN + lane * 2);
        a0 += w0 * bf2f((unsigned short)(v0 & 0xFFFF)); a1 += w0 * bf2f((unsigned short)(v0 >> 16));
        a0 += w1 * bf2f((unsigned short)(v1 & 0xFFFF)); a1 += w1 * bf2f((unsigned short)(v1 >> 16));
        a0 += w2 * bf2f((unsigned short)(v2 & 0xFFFF)); a1 += w2 * bf2f((unsigned short)(v2 >> 16));
        a0 += w3 * bf2f((unsigned short)(v3 & 0xFFFF)); a1 += w3 * bf2f((unsigned short)(v3 >> 16));
    }
    for (; k < e; ++k) {
        int j = csrc[k];
        float w = cw[k];
        unsigned int v = *(const unsigned int*)(xb + (size_t)j * FIN + lane * 2);
        a0 += w * bf2f((unsigned short)(v & 0xFFFF));
        a1 += w * bf2f((unsigned short)(v >> 16));
    }
    unsigned int o = (unsigned int)f2bf(a0) | ((unsigned int)f2bf(a1) << 16);
    *(unsigned int*)(out + (size_t)node * FIN + lane * 2) = o;
}

__global__ void k_agg512(const unsigned char* __restrict__ h8, const int* __restrict__ off,
                         const int* __restrict__ csrc, const float* __restrict__ cw,
                         unsigned short* __restrict__ out) {
    int node = blockIdx.x * 4 + (threadIdx.x >> 6);
    if (node >= NNODES) return;
    int lane = threadIdx.x & 63;
    float acc[8] = {};
    int s = off[node], e = off[node + 1];
    auto accum = [&](int2 v, float w) {
        f32x2 f01 = fp8pair2f<false>(v.x);
        f32x2 f23 = fp8pair2f<true>(v.x);
        f32x2 f45 = fp8pair2f<false>(v.y);
        f32x2 f67 = fp8pair2f<true>(v.y);
        acc[0] += w * f01.x; acc[1] += w * f01.y;
        acc[2] += w * f23.x; acc[3] += w * f23.y;
        acc[4] += w * f45.x; acc[5] += w * f45.y;
        acc[6] += w * f67.x; acc[7] += w * f67.y;
    };
    int k = s;
    for (; k + 3 < e; k += 4) {
        int j0 = csrc[k], j1 = csrc[k + 1], j2 = csrc[k + 2], j3 = csrc[k + 3];
        float w0 = cw[k], w1 = cw[k + 1], w2 = cw[k + 2], w3 = cw[k + 3];
        int2 v0 = *(const int2*)(h8 + (size_t)j0 * HID + lane * 8);
        int2 v1 = *(const int2*)(h8 + (size_t)j1 * HID + lane * 8);
        int2 v2 = *(const int2*)(h8 + (size_t)j2 * HID + lane * 8);
        int2 v3 = *(const int2*)(h8 + (size_t)j3 * HID + lane * 8);
        accum(v0, w0); accum(v1, w1); accum(v2, w2); accum(v3, w3);
    }
    for (; k < e; ++k) {
        int2 v = *(const int2*)(h8 + (size_t)csrc[k] * HID + lane * 8);
        accum(v, cw[k]);
    }
    bf16x8 o;
#pragma unroll
    for (int q = 0; q < 8; ++q) o[q] = (short)f2bf(acc[q]);
    *(bf16x8*)(out + (size_t)node * HID + lane * 8) = o;
}

// ---------------- dual MFMA GEMM: C = relu(A0@B0 + A1@B1 + bias) ----------------
// R14: ring depth 4 -> 3. LDS = 3*(10+16)KB = 78KB -> TWO blocks/CU (R13's
// 104KB ring was the hidden 1-block/CU cap; all schedule nulls R9-R12 were
// measured without cross-block overlap). VGPR 88 -> 4 waves/SIMD fits.
// Grid 500 at 2 blocks/CU -> single round, ~98% CU utilization.
// Depth-3 hazard ledger: at iter s, stage(s+2) overwrites buf (s-1)%3; its
// reads completed (lgkmcnt(0) before MFMA) ahead of the end-of-(s-1) barrier,
// which precedes iter s -> safe (1-barrier separation).
// vmcnt ledger (uniform 7 VMEM/thread/stage): prologue stages s0,s1 (14 out),
// vmcnt(7) drains s0; iter issues stage(s+2) (14 out), boundary vmcnt(7)
// drains exactly stage(s+1); never vmcnt(0) mid-loop.
// BM=160: B = 2x16B gload/thread; A = 5x4B gload/thread.
// Slot-XOR swizzle both sides (rule #21), verified 0 bank conflicts.
// GEMM1 (!POOL) epilogue dual-emits C (bf16) + C8 (fp8 e4m3) for the gather.

template <int K, bool POOL>
__global__ __launch_bounds__(512, 2)
void k_mfma_dual(const unsigned short* __restrict__ A0, const unsigned short* __restrict__ B0t,
                 const unsigned short* __restrict__ A1, const unsigned short* __restrict__ B1t,
                 const float* __restrict__ bias,
                 unsigned short* __restrict__ C, unsigned char* __restrict__ C8,
                 const int* __restrict__ batch, float* __restrict__ psum) {
    constexpr int KT = K / 32;       // sub-tiles per matrix
    constexpr int S = 2 * KT;        // total sub-tiles (two matrices)
    __shared__ unsigned short As[3][BM * 32];    // 10 KB per buf
    __shared__ unsigned short Bs[3][256 * 32];   // 16 KB per buf
    int tid = threadIdx.x;
    int l = tid & 63, w = tid >> 6;
    int wr = w >> 2, wc = w & 3;     // 2M x 4N waves, wave tile 80x64
    int bid = blockIdx.x;
    int row0 = (bid >> 1) * BM;
    int col0 = (bid & 1) * 256;

    int lr = l & 15, hi = l >> 4;
    int pofs = (hi ^ ((lr >> 1) & 3)) * 8;   // swizzled k-slot offset (ushorts)

    const unsigned short* Amat[2] = {A0, A1};
    const unsigned short* Bmat[2] = {B0t, B1t};

    // B staging (16B chunks): c: row r=c>>2, slot p=c&3, g = p ^ ((r>>1)&3)
    int bc0 = tid, bc1 = tid + 512;
    int br0 = bc0 >> 2, bg0 = (bc0 & 3) ^ ((br0 >> 1) & 3);
    int br1 = bc1 >> 2, bg1 = (bc1 & 3) ^ ((br1 >> 1) & 3);

    auto stage = [&](int s, int buf) {   // 7 VMEM/thread: 2x16B B + 5x4B A
        int mat = s / KT;
        int k0 = (s - mat * KT) * 32;
        const unsigned short* A = Amat[mat];
        const unsigned short* Bt = Bmat[mat];
        gload_lds16(Bt + (size_t)(col0 + br0) * K + k0 + bg0 * 8, &Bs[buf][bc0 * 8]);
        gload_lds16(Bt + (size_t)(col0 + br1) * K + k0 + bg1 * 8, &Bs[buf][bc1 * 8]);
#pragma unroll
        for (int q = 0; q < 5; ++q) {
            int c = tid + q * 512;            // 4B word id, 0..2559
            int r = c >> 4;                   // 16 words (64B) per row
            int g = ((c >> 2) & 3) ^ ((r >> 1) & 3);
            int u = c & 3;                    // word within 16B slot
            gload_lds4(A + (size_t)(row0 + r) * K + k0 + g * 8 + u * 2, &As[buf][c * 2]);
        }
    };

    // per-lane LDS byte addresses (32-bit LDS offsets)
    unsigned a_lane = (unsigned)(unsigned long long)&As[0][0]
                    + (unsigned)(((wr * 80 + lr) * 32 + pofs) * 2);
    unsigned b_lane = (unsigned)(unsigned long long)&Bs[0][0]
                    + (unsigned)(((wc * 64 + lr) * 32 + pofs) * 2);

    f32x4 acc[5][4];
#pragma unroll
    for (int m = 0; m < 5; ++m)
#pragma unroll
        for (int n = 0; n < 4; ++n) acc[m][n] = (f32x4)0.f;

    // prologue: stage s0 (buf0), s1 (buf1) -> 14 outstanding; drain s0 only.
    stage(0, 0);
    stage(1, 1);
    asm volatile("s_waitcnt vmcnt(7)" ::: "memory");
    __builtin_amdgcn_s_barrier();
    __builtin_amdgcn_sched_barrier(0);

    int buf = 0;                      // buf = s % 3, tracked incrementally
    int buf2 = 2;                     // (s+2) % 3
    for (int s = 0; s < S; ++s) {
        if (s + 2 < S) stage(s + 2, buf2);
        unsigned ab = a_lane + (unsigned)(buf * (BM * 32 * 2));
        unsigned bb = b_lane + (unsigned)(buf * (256 * 32 * 2));
        bf16x8 af[5], bfr[4];
        DS_READ_B128(af[0], ab, "0");
        DS_READ_B128(af[1], ab, "1024");
        DS_READ_B128(af[2], ab, "2048");
        DS_READ_B128(af[3], ab, "3072");
        DS_READ_B128(af[4], ab, "4096");
        DS_READ_B128(bfr[0], bb, "0");
        DS_READ_B128(bfr[1], bb, "1024");
        DS_READ_B128(bfr[2], bb, "2048");
        DS_READ_B128(bfr[3], bb, "3072");
        asm volatile("s_waitcnt lgkmcnt(0)" ::: "memory");
        __builtin_amdgcn_sched_barrier(0);   // rule #18
        __builtin_amdgcn_s_setprio(1);
#pragma unroll
        for (int m = 0; m < 3; ++m)
#pragma unroll
            for (int n = 0; n < 4; ++n)
                acc[m][n] = __builtin_amdgcn_mfma_f32_16x16x32_bf16(af[m], bfr[n], acc[m][n], 0, 0, 0);
        __builtin_amdgcn_s_setprio(0);
        __builtin_amdgcn_s_setprio(1);
#pragma unroll
        for (int m = 3; m < 5; ++m)
#pragma unroll
            for (int n = 0; n < 4; ++n)
                acc[m][n] = __builtin_amdgcn_mfma_f32_16x16x32_bf16(af[m], bfr[n], acc[m][n], 0, 0, 0);
        __builtin_amdgcn_s_setprio(0);
        // boundary: drain stage(s+1) only; keep stage(s+2) in flight
        if (s + 2 < S) {
            asm volatile("s_waitcnt vmcnt(7)" ::: "memory");
        } else {
            asm volatile("s_waitcnt vmcnt(0)" ::: "memory");
        }
        if (s + 1 < S) {
            __builtin_amdgcn_s_barrier();
            __builtin_amdgcn_sched_barrier(0);
        }
        buf = (buf == 2) ? 0 : buf + 1;
        buf2 = (buf2 == 2) ? 0 : buf2 + 1;
    }

    // epilogue: C/D layout col = l&15, row = (l>>4)*4 + i
    float bv[4];
#pragma unroll
    for (int n = 0; n < 4; ++n) bv[n] = bias[col0 + wc * 64 + n * 16 + lr];
    int rbase = row0 + wr * 80 + hi * 4;

    if constexpr (!POOL) {
#pragma unroll
        for (int m = 0; m < 5; ++m) {
#pragma unroll
            for (int i = 0; i < 4; ++i) {
                int rr = rbase + m * 16 + i;
                if (rr < NNODES) {
#pragma unroll
                    for (int n = 0; n < 4; ++n) {
                        int col = col0 + wc * 64 + n * 16 + lr;
                        float v = fmaxf(acc[m][n][i] + bv[n], 0.f);
                        C[(size_t)rr * HID + col] = f2bf(v);
                        C8[(size_t)rr * HID + col] = f2fp8(v);
                    }
                }
            }
        }
    } else {
#pragma unroll
        for (int m = 0; m < 5; ++m) {
            int b[4];
#pragma unroll
            for (int i = 0; i < 4; ++i) {
                int rr = rbase + m * 16 + i;
                b[i] = (rr < NNODES) ? batch[rr] : -1;
            }
#pragma unroll
            for (int n = 0; n < 4; ++n) {
                int col = col0 + wc * 64 + n * 16 + lr;
                int cb = -1;
                float run = 0.f;
#pragma unroll
                for (int i = 0; i < 4; ++i) {
                    if (b[i] >= 0) {
                        float v = fmaxf(acc[m][n][i] + bv[n], 0.f);
                        if (b[i] == cb) {
                            run += v;
                        } else {
                            if (cb >= 0) atomicAdd(&psum[(size_t)cb * HID + col], run);
                            cb = b[i];
                            run = v;
                        }
                    }
                }
                if (cb >= 0) atomicAdd(&psum[(size_t)cb * HID + col], run);
            }
        }
    }
}

// ---------------- pooling count (LDS histogram) + MLP head (fp32) ----------------

__global__ void k_cnt(const int* __restrict__ batch, float* __restrict__ cnt) {
    __shared__ int h[NGRAPH];
    int t = threadIdx.x;
    if (t < NGRAPH) h[t] = 0;
    __syncthreads();
    int i = blockIdx.x * 256 + t;
    if (i < NNODES) atomicAdd(&h[batch[i]], 1);
    __syncthreads();
    if (t < NGRAPH && h[t] != 0) atomicAdd(&cnt[t], (float)h[t]);
}

__global__ void k_head(const float* __restrict__ psum, const float* __restrict__ cnt,
                       const float* __restrict__ W1, const float* __restrict__ b1,
                       const float* __restrict__ W2, const float* __restrict__ b2,
                       const float* __restrict__ W3, const float* __restrict__ b3,
                       float* __restrict__ out) {
    __shared__ float pooled[HID];
    __shared__ float o1[64];
    __shared__ float o2[16];
    int g = blockIdx.x, t = threadIdx.x;
    float c = fmaxf(cnt[g], 1.0f);
    for (int k = t; k < HID; k += 64) pooled[k] = psum[(size_t)g * HID + k] / c;
    __syncthreads();
    float a = b1[t];
    for (int k = 0; k < HID; ++k) a += pooled[k] * W1[k * 64 + t];
    o1[t] = fmaxf(a, 0.f);
    __syncthreads();
    if (t < 16) {
        float a2 = b2[t];
        for (int k = 0; k < 64; ++k) a2 += o1[k] * W2[k * 16 + t];
        o2[t] = fmaxf(a2, 0.f);
    }
    __syncthreads();
    if (t == 0) {
        float a3 = b3[0];
        for (int k = 0; k < 16; ++k) a3 += o2[k] * W3[k];
        out[g] = a3;
    }
}

// ---------------- launch ----------------

extern "C" void kernel_launch(void* const* d_in, const int* in_sizes, int n_in,
                              void* d_out, int out_size, void* d_ws, size_t ws_size,
                              hipStream_t stream) {
    const float* x = (const float*)d_in[0];
    const int* ei = (const int*)d_in[1];
    const int* src = ei;
    const int* dst = ei + NEDGES;
    const float* ew = (const float*)d_in[2];
    const int* batch = (const int*)d_in[3];
    const float* Wr1 = (const float*)d_in[4];
    const float* br1 = (const float*)d_in[5];
    const float* Wo1 = (const float*)d_in[6];
    const float* Wr2 = (const float*)d_in[7];
    const float* br2 = (const float*)d_in[8];
    const float* Wo2 = (const float*)d_in[9];
    const float* W1 = (const float*)d_in[10];
    const float* b1 = (const float*)d_in[11];
    const float* W2 = (const float*)d_in[12];
    const float* b2 = (const float*)d_in[13];
    const float* W3 = (const float*)d_in[14];
    const float* b3 = (const float*)d_in[15];
    float* out = (float*)d_out;

    char* ws = (char*)d_ws;
    size_t o = 0;
    auto alloc = [&](size_t bytes) -> void* {
        void* p = ws + o;
        o = (o + bytes + 255) & ~(size_t)255;
        return p;
    };
    int* deg = (int*)alloc((size_t)NNODES * 4);
    int* off = (int*)alloc((size_t)(NNODES + 1) * 4);
    int* cur = (int*)alloc((size_t)NNODES * 4);
    int* csrc = (int*)alloc((size_t)NEDGES * 4);
    float* cw = (float*)alloc((size_t)NEDGES * 4);
    unsigned short* xb = (unsigned short*)alloc((size_t)MPAD * FIN * 2);
    unsigned short* agg1 = (unsigned short*)alloc((size_t)MPAD * FIN * 2);
    unsigned short* h1 = (unsigned short*)alloc((size_t)MPAD * HID * 2);
    unsigned char* h1f8 = (unsigned char*)alloc((size_t)MPAD * HID);
    unsigned short* agg2 = (unsigned short*)alloc((size_t)MPAD * HID * 2);
    unsigned short* Wr1t = (unsigned short*)alloc((size_t)512 * FIN * 2);
    unsigned short* Wo1t = (unsigned short*)alloc((size_t)512 * FIN * 2);
    unsigned short* Wr2t = (unsigned short*)alloc((size_t)512 * HID * 2);
    unsigned short* Wo2t = (unsigned short*)alloc((size_t)512 * HID * 2);
    float* psum = (float*)alloc((size_t)NGRAPH * HID * 4);
    float* cnt = (float*)alloc((size_t)NGRAPH * 4);

    hipMemsetAsync(deg, 0, (size_t)NNODES * 4, stream);
    hipMemsetAsync(psum, 0, (size_t)NGRAPH * HID * 4, stream);
    hipMemsetAsync(cnt, 0, (size_t)NGRAPH * 4, stream);

    // conversions
    k_cvt_x<<<((MPAD * FIN / 8) + 255) / 256, 256, 0, stream>>>(x, xb);
    k_cvt_wt<<<(512 * FIN + 255) / 256, 256, 0, stream>>>(Wr1, Wr1t, FIN);
    k_cvt_wt<<<(512 * FIN + 255) / 256, 256, 0, stream>>>(Wo1, Wo1t, FIN);
    k_cvt_wt<<<(512 * HID + 255) / 256, 256, 0, stream>>>(Wr2, Wr2t, HID);
    k_cvt_wt<<<(512 * HID + 255) / 256, 256, 0, stream>>>(Wo2, Wo2t, HID);

    // CSR
    k_deg<<<(NEDGES + 255) / 256, 256, 0, stream>>>(dst, deg);
    k_scan<<<1, 1024, 0, stream>>>(deg, off, cur);
    k_fill<<<(NEDGES + 255) / 256, 256, 0, stream>>>(src, dst, ew, cur, csrc, cw);

    // layer 1
    k_agg128<<<(NNODES + 3) / 4, 256, 0, stream>>>(xb, off, csrc, cw, agg1);
    int nblk = (MPAD / BM) * 2;   // 500 blocks; col in low bit
    k_mfma_dual<FIN, false><<<nblk, 512, 0, stream>>>(agg1, Wr1t, xb, Wo1t, br1, h1, h1f8, nullptr, nullptr);

    // layer 2 (+ fused mean-pool numerator)
    k_agg512<<<(NNODES + 3) / 4, 256, 0, stream>>>(h1f8, off, csrc, cw, agg2);
    k_cnt<<<(NNODES + 255) / 256, 256, 0, stream>>>(batch, cnt);
    k_mfma_dual<HID, true><<<nblk, 512, 0, stream>>>(agg2, Wr2t, h1, Wo2t, br2, nullptr, nullptr, batch, psum);

    // head
    k_head<<<NGRAPH, 64, 0, stream>>>(psum, cnt, W1, b1, W2, b2, W3, b3, out);
}